// Round 1
// baseline (167.428 us; speedup 1.0000x reference)
//
#include <hip/hip_runtime.h>
#include <math.h>

#define NSUB   2048
#define NTRIAL 40
#define NPATH  12341
#define NITER  ((NPATH + 255) / 256)   // 49

// ---------------------------------------------------------------------------
// Kernel 1: parameter transforms (tiny). params layout (floats):
//   [0..15]  log p_state_responses[state*4 + response]
//   [16..19] log p_state_priors
//   [20..35] log p_transitions[from*4 + to]  (-1e30 for to<from, unused)
// ---------------------------------------------------------------------------
__global__ void param_kernel(const float* __restrict__ w_ss,
                             const float* __restrict__ w_sp,
                             const float* __restrict__ w_tr,
                             float* __restrict__ params) {
    if (threadIdx.x != 0 || blockIdx.x != 0) return;
    const float psr[4][4] = {
        {3.f/9.f, 4.f/9.f, 1.f/9.f, 1.f/9.f},
        {0.f,     4.f/6.f, 1.f/6.f, 1.f/6.f},
        {0.f,     0.f,     0.5f,    0.5f},
        {0.f,     0.f,     0.f,     1.f}};
    // p_strategy_success: row-wise softmax over lower-triangular (j<=i)
    float pss[4][4];
    for (int i = 0; i < 4; i++) {
        float m = -1e30f;
        for (int j = 0; j <= i; j++) m = fmaxf(m, w_ss[i*4+j]);
        float e[4] = {0.f,0.f,0.f,0.f}, s = 0.f;
        for (int j = 0; j <= i; j++) { e[j] = __expf(w_ss[i*4+j] - m); s += e[j]; }
        for (int j = 0; j < 4; j++) pss[i][j] = (j <= i) ? e[j]/s : 0.f;
    }
    // log p_state_responses = log(pss @ psr)
    for (int i = 0; i < 4; i++)
        for (int r = 0; r < 4; r++) {
            float acc = 0.f;
            for (int j = 0; j < 4; j++) acc += pss[i][j] * psr[j][r];
            params[i*4+r] = logf(acc);
        }
    // log p_state_priors
    {
        float m = fmaxf(fmaxf(w_sp[0], w_sp[1]), fmaxf(w_sp[2], w_sp[3]));
        float e[4], s = 0.f;
        for (int k = 0; k < 4; k++) { e[k] = __expf(w_sp[k] - m); s += e[k]; }
        for (int k = 0; k < 4; k++) params[16+k] = logf(e[k]/s);
    }
    // log p_transitions: row-wise softmax over upper-triangular (j>=i)
    for (int i = 0; i < 4; i++) {
        float m = -1e30f;
        for (int j = i; j < 4; j++) m = fmaxf(m, w_tr[i*4+j]);
        float e[4] = {0.f,0.f,0.f,0.f}, s = 0.f;
        for (int j = i; j < 4; j++) { e[j] = __expf(w_tr[i*4+j] - m); s += e[j]; }
        for (int j = 0; j < 4; j++)
            params[20+i*4+j] = (j >= i) ? logf(e[j]/s) : -1e30f;
    }
}

// ---------------------------------------------------------------------------
// Kernel 2: per-path decode. Monotone path -> breakpoints (t1,t2,t3) =
// counts of trials in states <=0, <=1, <=2; plus log P(path).
// ---------------------------------------------------------------------------
__global__ void path_kernel(const int* __restrict__ paths,
                            const float* __restrict__ params,
                            float* __restrict__ logp,
                            int* __restrict__ bp) {
    int p = blockIdx.x * blockDim.x + threadIdx.x;
    if (p >= NPATH) return;
    const int* pp = paths + (size_t)p * NTRIAL;
    int s0 = pp[0];
    float lp = params[16 + s0];
    int c0 = (s0 == 0), c1 = (s0 <= 1), c2 = (s0 <= 2);
    int prev = s0;
    for (int t = 1; t < NTRIAL; t++) {
        int st = pp[t];
        lp += params[20 + prev*4 + st];
        c0 += (st == 0); c1 += (st <= 1); c2 += (st <= 2);
        prev = st;
    }
    logp[p] = lp;
    bp[p] = c0 | (c1 << 6) | (c2 << 12);
}

// ---------------------------------------------------------------------------
// Kernel 3: one block per subject. Prefix sums C[k][t] in LDS, then
// numerators into a register array + block-sum, then normalized write.
// ---------------------------------------------------------------------------
__global__ __launch_bounds__(256) void post_kernel(
        const int* __restrict__ resp,
        const float* __restrict__ params,
        const float* __restrict__ logp,
        const int* __restrict__ bp,
        float* __restrict__ out) {
    __shared__ float C[4][44];   // C[k][t], t = 0..NTRIAL
    __shared__ int   rs[NTRIAL];
    __shared__ float red[4];
    __shared__ float s_inv;

    const int s = blockIdx.x;
    const int tid = threadIdx.x;

    if (tid < NTRIAL) rs[tid] = resp[(size_t)s * NTRIAL + tid];
    __syncthreads();
    if (tid < 4) {
        float c = 0.f;
        C[tid][0] = 0.f;
        for (int t = 0; t < NTRIAL; t++) {
            c += params[tid*4 + rs[t]];
            C[tid][t+1] = c;
        }
    }
    __syncthreads();
    const float CT3 = C[3][NTRIAL];

    float nums[NITER];
    float lsum = 0.f;
#pragma unroll
    for (int i = 0; i < NITER; i++) {
        int p = tid + 256 * i;
        float v = 0.f;
        if (p < NPATH) {
            int b  = bp[p];
            int t1 = b & 63, t2 = (b >> 6) & 63, t3 = (b >> 12) & 63;
            float ll = C[0][t1] + (C[1][t2] - C[1][t1])
                     + (C[2][t3] - C[2][t2]) + (CT3 - C[3][t3]);
            v = __expf(logp[p] + ll);
        }
        nums[i] = v;
        lsum += v;
    }

    // block reduction (wave64 shuffle, then cross-wave via LDS)
    for (int off = 32; off > 0; off >>= 1)
        lsum += __shfl_down(lsum, off, 64);
    const int wave = tid >> 6, lane = tid & 63;
    if (lane == 0) red[wave] = lsum;
    __syncthreads();
    if (tid == 0) s_inv = 1.f / (red[0] + red[1] + red[2] + red[3]);
    __syncthreads();
    const float inv = s_inv;

    float* orow = out + (size_t)s * NPATH;
#pragma unroll
    for (int i = 0; i < NITER; i++) {
        int p = tid + 256 * i;
        if (p < NPATH) orow[p] = nums[i] * inv;
    }
}

// ---------------------------------------------------------------------------
extern "C" void kernel_launch(void* const* d_in, const int* in_sizes, int n_in,
                              void* d_out, int out_size, void* d_ws, size_t ws_size,
                              hipStream_t stream) {
    const int*   resp  = (const int*)d_in[0];
    const int*   paths = (const int*)d_in[1];
    const float* w_ss  = (const float*)d_in[2];
    const float* w_sp  = (const float*)d_in[3];
    const float* w_tr  = (const float*)d_in[4];
    float* out = (float*)d_out;

    float* params = (float*)d_ws;            // 64 floats
    float* logp   = params + 64;             // NPATH floats
    int*   bp     = (int*)(params + 64 + 12352);  // NPATH ints (aligned)

    param_kernel<<<1, 64, 0, stream>>>(w_ss, w_sp, w_tr, params);
    path_kernel<<<(NPATH + 255) / 256, 256, 0, stream>>>(paths, params, logp, bp);
    post_kernel<<<NSUB, 256, 0, stream>>>(resp, params, logp, bp, out);
}

// Round 2
// 147.219 us; speedup vs baseline: 1.1373x; 1.1373x over previous
//
#include <hip/hip_runtime.h>
#include <math.h>

#define NSUB   2048
#define NTRIAL 40
#define NPATH  12341
#define PBLK   1024
#define NIT    ((NPATH + PBLK - 1) / PBLK)   // 13

// ---------------------------------------------------------------------------
// Kernel 1: per-path decode. Monotone path -> packed breakpoints
// (t1,t2,t3) = counts of trials in states <=0, <=1, <=2, and log P(path).
// Record: int2 { float logp (bitcast), int bp }.
// Params (log-softmax of priors/transitions) recomputed per block (tiny).
// ---------------------------------------------------------------------------
__global__ __launch_bounds__(256) void path_kernel(
        const int* __restrict__ paths,
        const float* __restrict__ w_sp,
        const float* __restrict__ w_tr,
        int2* __restrict__ rec) {
    __shared__ float sprior[4];
    __shared__ float str[16];
    const int tid = threadIdx.x;

    if (tid < 4) {
        // log-softmax of priors
        float m = fmaxf(fmaxf(w_sp[0], w_sp[1]), fmaxf(w_sp[2], w_sp[3]));
        float s = 0.f;
        for (int k = 0; k < 4; k++) s += __expf(w_sp[k] - m);
        sprior[tid] = w_sp[tid] - (__logf(s) + m);
    } else if (tid < 20) {
        // log-softmax row i of transitions over j>=i (upper-triangular)
        int idx = tid - 4, i = idx >> 2, j = idx & 3;
        float m = -1e30f;
        for (int k = i; k < 4; k++) m = fmaxf(m, w_tr[i*4 + k]);
        float s = 0.f;
        for (int k = i; k < 4; k++) s += __expf(w_tr[i*4 + k] - m);
        str[idx] = (j >= i) ? (w_tr[i*4 + j] - (__logf(s) + m)) : 0.f;
    }
    __syncthreads();

    int p = blockIdx.x * 256 + tid;
    if (p >= NPATH) return;

    const int4* pp = (const int4*)(paths + (size_t)p * NTRIAL);
    int st[NTRIAL];
#pragma unroll
    for (int q = 0; q < NTRIAL / 4; q++) {
        int4 v = pp[q];
        st[4*q] = v.x; st[4*q+1] = v.y; st[4*q+2] = v.z; st[4*q+3] = v.w;
    }
    float lp = sprior[st[0]];
    int c0 = (st[0] == 0), c1 = (st[0] <= 1), c2 = (st[0] <= 2);
#pragma unroll
    for (int t = 1; t < NTRIAL; t++) {
        lp += str[st[t-1]*4 + st[t]];
        c0 += (st[t] == 0); c1 += (st[t] <= 1); c2 += (st[t] <= 2);
    }
    rec[p] = make_int2(__float_as_int(lp), c0 | (c1 << 6) | (c2 << 12));
}

// ---------------------------------------------------------------------------
// Kernel 2: one block (1024 thr) per subject.
// ll(p) = D1[t1] + D2[t2] + D3[t3] + CT3  (3 LDS reads per element).
// ---------------------------------------------------------------------------
__global__ __launch_bounds__(1024) void post_kernel(
        const int* __restrict__ resp,
        const float* __restrict__ w_ss,
        const int2* __restrict__ rec,
        float* __restrict__ out) {
    __shared__ float lsr[16];            // log p_state_responses
    __shared__ int   rs[NTRIAL];
    __shared__ float C[4][NTRIAL + 1];
    __shared__ float D1[NTRIAL + 1], D2[NTRIAL + 1], D3[NTRIAL + 1];
    __shared__ float red[16];
    __shared__ float bcast[2];           // [0]=CT3, [1]=inv_sum

    const int s = blockIdx.x;
    const int tid = threadIdx.x;

    if (tid < 16) {
        // lsr[i][r] = log( sum_j softmax(w_ss row i, j<=i)[j] * psr[j][r] )
        const float psr[4][4] = {
            {3.f/9.f, 4.f/9.f, 1.f/9.f, 1.f/9.f},
            {0.f,     4.f/6.f, 1.f/6.f, 1.f/6.f},
            {0.f,     0.f,     0.5f,    0.5f},
            {0.f,     0.f,     0.f,     1.f}};
        int i = tid >> 2, r = tid & 3;
        float m = -1e30f;
        for (int j = 0; j <= i; j++) m = fmaxf(m, w_ss[i*4 + j]);
        float e[4] = {0.f,0.f,0.f,0.f}, ssum = 0.f;
        for (int j = 0; j <= i; j++) { e[j] = __expf(w_ss[i*4 + j] - m); ssum += e[j]; }
        float acc = 0.f;
        for (int j = 0; j <= i; j++) acc += (e[j] / ssum) * psr[j][r];
        lsr[tid] = __logf(acc);
    }
    if (tid < NTRIAL) rs[tid] = resp[(size_t)s * NTRIAL + tid];
    __syncthreads();

    if (tid < 4) {
        float c = 0.f;
        C[tid][0] = 0.f;
        for (int t = 0; t < NTRIAL; t++) {
            c += lsr[tid*4 + rs[t]];
            C[tid][t+1] = c;
        }
    }
    __syncthreads();
    if (tid <= NTRIAL) {
        D1[tid] = C[0][tid] - C[1][tid];
        D2[tid] = C[1][tid] - C[2][tid];
        D3[tid] = C[2][tid] - C[3][tid];
    }
    if (tid == 0) bcast[0] = C[3][NTRIAL];
    __syncthreads();
    const float CT3 = bcast[0];

    float nums[NIT];
    float lsum = 0.f;
#pragma unroll
    for (int i = 0; i < NIT; i++) {
        int p = tid + PBLK * i;
        float v = 0.f;
        if (p < NPATH) {
            int2 r2 = rec[p];
            int b = r2.y;
            int t1 = b & 63, t2 = (b >> 6) & 63, t3 = (b >> 12) & 63;
            v = __expf(__int_as_float(r2.x) + D1[t1] + D2[t2] + D3[t3] + CT3);
        }
        nums[i] = v;
        lsum += v;
    }

    // wave64 shuffle reduce, then cross-wave via LDS
    for (int off = 32; off > 0; off >>= 1)
        lsum += __shfl_down(lsum, off, 64);
    const int wave = tid >> 6, lane = tid & 63;
    if (lane == 0) red[wave] = lsum;
    __syncthreads();
    if (tid == 0) {
        float t = 0.f;
        for (int w = 0; w < 16; w++) t += red[w];
        bcast[1] = 1.f / t;
    }
    __syncthreads();
    const float inv = bcast[1];

    float* orow = out + (size_t)s * NPATH;
#pragma unroll
    for (int i = 0; i < NIT; i++) {
        int p = tid + PBLK * i;
        if (p < NPATH) orow[p] = nums[i] * inv;
    }
}

// ---------------------------------------------------------------------------
extern "C" void kernel_launch(void* const* d_in, const int* in_sizes, int n_in,
                              void* d_out, int out_size, void* d_ws, size_t ws_size,
                              hipStream_t stream) {
    const int*   resp  = (const int*)d_in[0];
    const int*   paths = (const int*)d_in[1];
    const float* w_ss  = (const float*)d_in[2];
    const float* w_sp  = (const float*)d_in[3];
    const float* w_tr  = (const float*)d_in[4];
    float* out = (float*)d_out;

    int2* rec = (int2*)d_ws;   // NPATH records (8 B each)

    path_kernel<<<(NPATH + 255) / 256, 256, 0, stream>>>(paths, w_sp, w_tr, rec);
    post_kernel<<<NSUB, PBLK, 0, stream>>>(resp, w_ss, rec, out);
}

// Round 3
// 135.148 us; speedup vs baseline: 1.2389x; 1.0893x over previous
//
#include <hip/hip_runtime.h>
#include <math.h>

#define NSUB   2048
#define NTRIAL 40
#define NPATH  12341
#define PBLK   1024
#define NFULL  (NPATH / PBLK)          // 12 full iterations (12288 paths)
#define NTAIL  (NPATH - NFULL * PBLK)  // 53 remainder paths

// ---------------------------------------------------------------------------
// Kernel 1: per-path decode. Monotone path -> packed breakpoints
// (t1,t2,t3) = counts of trials in states <=0, <=1, <=2, and log P(path).
// Record: int2 { float logp (bitcast), int bp }.
// ---------------------------------------------------------------------------
__global__ __launch_bounds__(256) void path_kernel(
        const int* __restrict__ paths,
        const float* __restrict__ w_sp,
        const float* __restrict__ w_tr,
        int2* __restrict__ rec) {
    __shared__ float sprior[4];
    __shared__ float str[16];
    const int tid = threadIdx.x;

    if (tid < 4) {
        float m = fmaxf(fmaxf(w_sp[0], w_sp[1]), fmaxf(w_sp[2], w_sp[3]));
        float s = 0.f;
        for (int k = 0; k < 4; k++) s += __expf(w_sp[k] - m);
        sprior[tid] = w_sp[tid] - (__logf(s) + m);
    } else if (tid < 20) {
        int idx = tid - 4, i = idx >> 2, j = idx & 3;
        float m = -1e30f;
        for (int k = i; k < 4; k++) m = fmaxf(m, w_tr[i*4 + k]);
        float s = 0.f;
        for (int k = i; k < 4; k++) s += __expf(w_tr[i*4 + k] - m);
        str[idx] = (j >= i) ? (w_tr[i*4 + j] - (__logf(s) + m)) : 0.f;
    }
    __syncthreads();

    int p = blockIdx.x * 256 + tid;
    if (p >= NPATH) return;

    const int4* pp = (const int4*)(paths + (size_t)p * NTRIAL);
    int st[NTRIAL];
#pragma unroll
    for (int q = 0; q < NTRIAL / 4; q++) {
        int4 v = pp[q];
        st[4*q] = v.x; st[4*q+1] = v.y; st[4*q+2] = v.z; st[4*q+3] = v.w;
    }
    float lp = sprior[st[0]];
    int c0 = (st[0] == 0), c1 = (st[0] <= 1), c2 = (st[0] <= 2);
#pragma unroll
    for (int t = 1; t < NTRIAL; t++) {
        lp += str[st[t-1]*4 + st[t]];
        c0 += (st[t] == 0); c1 += (st[t] <= 1); c2 += (st[t] <= 2);
    }
    rec[p] = make_int2(__float_as_int(lp), c0 | (c1 << 6) | (c2 << 12));
}

// ---------------------------------------------------------------------------
// Kernel 2: one block (1024 thr) per subject.
// numerator(p) = exp(logp + D1[t1] + D2[t2] + D3[t3])   (CT3 folded into D3)
// Guard-free main loop: 12 iterations cover p < 12288; 53-path tail separate.
// All rec loads issued up-front for max memory-level parallelism.
// ---------------------------------------------------------------------------
__global__ __launch_bounds__(1024) void post_kernel(
        const int* __restrict__ resp,
        const float* __restrict__ w_ss,
        const int2* __restrict__ rec,
        float* __restrict__ out) {
    __shared__ float lsr[16];            // log p_state_responses
    __shared__ int   rs[NTRIAL];
    __shared__ float C[4][NTRIAL + 1];
    __shared__ float D1[NTRIAL + 1], D2[NTRIAL + 1], D3[NTRIAL + 1];
    __shared__ float red[16];
    __shared__ float s_inv;

    const int s = blockIdx.x;
    const int tid = threadIdx.x;

    if (tid < 16) {
        const float psr[4][4] = {
            {3.f/9.f, 4.f/9.f, 1.f/9.f, 1.f/9.f},
            {0.f,     4.f/6.f, 1.f/6.f, 1.f/6.f},
            {0.f,     0.f,     0.5f,    0.5f},
            {0.f,     0.f,     0.f,     1.f}};
        int i = tid >> 2, r = tid & 3;
        float m = -1e30f;
        for (int j = 0; j <= i; j++) m = fmaxf(m, w_ss[i*4 + j]);
        float e[4] = {0.f,0.f,0.f,0.f}, ssum = 0.f;
        for (int j = 0; j <= i; j++) { e[j] = __expf(w_ss[i*4 + j] - m); ssum += e[j]; }
        float acc = 0.f;
        for (int j = 0; j <= i; j++) acc += (e[j] / ssum) * psr[j][r];
        lsr[tid] = __logf(acc);
    }
    if (tid < NTRIAL) rs[tid] = resp[(size_t)s * NTRIAL + tid];
    __syncthreads();

    if (tid < 4) {
        float c = 0.f;
        C[tid][0] = 0.f;
        for (int t = 0; t < NTRIAL; t++) {
            c += lsr[tid*4 + rs[t]];
            C[tid][t+1] = c;
        }
    }
    __syncthreads();
    if (tid <= NTRIAL) {
        float ct3 = C[3][NTRIAL];
        D1[tid] = C[0][tid] - C[1][tid];
        D2[tid] = C[1][tid] - C[2][tid];
        D3[tid] = C[2][tid] - C[3][tid] + ct3;
    }
    __syncthreads();

    // ---- load all rec records up front (12 outstanding dwordx2 + tail) ----
    int2 r[NFULL];
#pragma unroll
    for (int i = 0; i < NFULL; i++) r[i] = rec[tid + PBLK * i];
    const bool tail = (tid < NTAIL);
    int2 rt = tail ? rec[NFULL * PBLK + tid] : make_int2(0, 0);

    float nums[NFULL];
    float lsum = 0.f;
#pragma unroll
    for (int i = 0; i < NFULL; i++) {
        int b = r[i].y;
        int t1 = b & 63, t2 = (b >> 6) & 63, t3 = (b >> 12) & 63;
        float v = __expf(__int_as_float(r[i].x) + D1[t1] + D2[t2] + D3[t3]);
        nums[i] = v;
        lsum += v;
    }
    float numt = 0.f;
    if (tail) {
        int b = rt.y;
        int t1 = b & 63, t2 = (b >> 6) & 63, t3 = (b >> 12) & 63;
        numt = __expf(__int_as_float(rt.x) + D1[t1] + D2[t2] + D3[t3]);
        lsum += numt;
    }

    // wave64 shuffle reduce, then cross-wave via LDS
    for (int off = 32; off > 0; off >>= 1)
        lsum += __shfl_down(lsum, off, 64);
    const int wave = tid >> 6, lane = tid & 63;
    if (lane == 0) red[wave] = lsum;
    __syncthreads();
    if (tid == 0) {
        float t = 0.f;
        for (int w = 0; w < 16; w++) t += red[w];
        s_inv = 1.f / t;
    }
    __syncthreads();
    const float inv = s_inv;

    float* orow = out + (size_t)s * NPATH;
#pragma unroll
    for (int i = 0; i < NFULL; i++)
        orow[tid + PBLK * i] = nums[i] * inv;
    if (tail)
        orow[NFULL * PBLK + tid] = numt * inv;
}

// ---------------------------------------------------------------------------
extern "C" void kernel_launch(void* const* d_in, const int* in_sizes, int n_in,
                              void* d_out, int out_size, void* d_ws, size_t ws_size,
                              hipStream_t stream) {
    const int*   resp  = (const int*)d_in[0];
    const int*   paths = (const int*)d_in[1];
    const float* w_ss  = (const float*)d_in[2];
    const float* w_sp  = (const float*)d_in[3];
    const float* w_tr  = (const float*)d_in[4];
    float* out = (float*)d_out;

    int2* rec = (int2*)d_ws;   // NPATH records (8 B each)

    path_kernel<<<(NPATH + 255) / 256, 256, 0, stream>>>(paths, w_sp, w_tr, rec);
    post_kernel<<<NSUB, PBLK, 0, stream>>>(resp, w_ss, rec, out);
}